// Round 2
// baseline (352.469 us; speedup 1.0000x reference)
//
#include <hip/hip_runtime.h>
#include <hip/hip_bf16.h>

// GQA + RoPE fused block for MI355X (gfx950).
// B=2, T=2048, D=2048, H=32, HKV=8, DH=64, G=4.
// bf16 MFMA 16x16x32 for QKV proj, attention, out proj. fp32 softmax/RoPE.
// Flash v7 = v6 (P-in-registers via permuted V, 1-barrier dbuf) restructured to
// 128-row Q tiles / 32 q-rows per wave: each K/V LDS fragment read now feeds up
// to 4 MFMAs (2 row-groups x 2 causal-paired halves) instead of 1. LDS-read
// traffic per CU drops 2.6x (8448 -> 3200 b128/CU) -- the r1 counters showed
// flash is LDS-read-BW bound (42us of 71us in ds_read at 12cyc each).
// r4 lesson: no pointer-param lambdas (scratch spill).

typedef __bf16 bf16_t;
typedef __bf16 bf16x4 __attribute__((ext_vector_type(4)));
typedef __bf16 bf16x8 __attribute__((ext_vector_type(8)));
typedef float f32x4 __attribute__((ext_vector_type(4)));

#define B_ 2
#define T_ 2048
#define D_ 2048
#define H_ 32
#define HKV_ 8
#define DH_ 64

// 2^x via v_exp_f32 (avoid glibc __exp2f macro clash)
__device__ __forceinline__ float fast_exp2(float x) { return __builtin_amdgcn_exp2f(x); }

// async global->LDS, 16B per lane. LDS dest must be wave-uniform base; lane i
// deposits at base + 16*i (no padding allowed in the staged region).
__device__ __forceinline__ void gld_lds16(const bf16_t* g, bf16_t* l) {
  __builtin_amdgcn_global_load_lds((const __attribute__((address_space(1))) unsigned int*)g,
                                   (__attribute__((address_space(3))) unsigned int*)l, 16, 0, 0);
}

// ---------------------------------------------------------------- cast x -> bf16
__global__ __launch_bounds__(256) void cast_f32_bf16(const float* __restrict__ in,
                                                     bf16_t* __restrict__ out, int n) {
  int i = (blockIdx.x * 256 + threadIdx.x) * 8;
  if (i < n) {
    f32x4 a = *(const f32x4*)&in[i];
    f32x4 b = *(const f32x4*)&in[i + 4];
    bf16x8 o;
    o[0] = (bf16_t)a[0]; o[1] = (bf16_t)a[1]; o[2] = (bf16_t)a[2]; o[3] = (bf16_t)a[3];
    o[4] = (bf16_t)b[0]; o[5] = (bf16_t)b[1]; o[6] = (bf16_t)b[2]; o[7] = (bf16_t)b[3];
    *(bf16x8*)&out[i] = o;
  }
}

// ------------------------------------------- transpose + cast: W[K][N] -> Wt[N][K]
__global__ __launch_bounds__(256) void transpose_w(const float* __restrict__ W,
                                                   bf16_t* __restrict__ Wt, int K, int N) {
  __shared__ float tile[64][65];
  int n0 = blockIdx.x * 64, k0 = blockIdx.y * 64;
  int tid = threadIdx.x;
  for (int i = tid; i < 4096; i += 256) {
    int r = i >> 6, c = i & 63;
    tile[r][c] = W[(size_t)(k0 + r) * N + n0 + c];
  }
  __syncthreads();
  for (int i = tid; i < 4096; i += 256) {
    int r = i >> 6, c = i & 63;
    Wt[(size_t)(n0 + r) * K + k0 + c] = (bf16_t)tile[c][r];
  }
}

// --------------------- fused transpose+cast of Wq|Wk|Wv into wqkvb[3072][2048]
__global__ __launch_bounds__(256) void transpose_wqkv(const float* __restrict__ Wq,
                                                      const float* __restrict__ Wk,
                                                      const float* __restrict__ Wv,
                                                      bf16_t* __restrict__ Wt) {
  __shared__ float tile[64][65];
  int n0 = blockIdx.x * 64, k0 = blockIdx.y * 64;
  const float* W;
  int srcN, col;
  if (n0 < 2048) { W = Wq; srcN = 2048; col = n0; }
  else if (n0 < 2560) { W = Wk; srcN = 512; col = n0 - 2048; }
  else { W = Wv; srcN = 512; col = n0 - 2560; }
  int tid = threadIdx.x;
  for (int i = tid; i < 4096; i += 256) {
    int r = i >> 6, c = i & 63;
    tile[r][c] = W[(size_t)(k0 + r) * srcN + col + c];
  }
  __syncthreads();
  for (int i = tid; i < 4096; i += 256) {
    int r = i >> 6, c = i & 63;
    Wt[(size_t)(n0 + r) * 2048 + k0 + c] = (bf16_t)tile[c][r];
  }
}

// ---------------------------------------------------------------- bf16 MFMA GEMM
// m97 structure, BK=64 as two concatenated stride-32 sub-blocks: keeps the
// bank-optimal 32-elem row stride and gld_lds16 lane order; halves barriers.
template <typename OutT>
__global__ __launch_bounds__(256) void gemm_bt(const bf16_t* __restrict__ A,
                                               const bf16_t* __restrict__ Bt,
                                               OutT* __restrict__ C, int M, int N, int K) {
  __shared__ __align__(16) bf16_t As[2 * 128 * 32];
  __shared__ __align__(16) bf16_t Bs[2 * 128 * 32];
  int tid = threadIdx.x;
  int lane = tid & 63;
  int wave = tid >> 6;
  int l15 = lane & 15;
  int quad = lane >> 4;
  int m0 = blockIdx.y * 128;
  int n0 = blockIdx.x * 128;
  int wrow = (wave >> 1) * 64;
  int wcol = (wave & 1) * 64;

  f32x4 acc[4][4] = {};

  for (int kc = 0; kc < K; kc += 64) {
#pragma unroll
    for (int kk = 0; kk < 2; ++kk) {
#pragma unroll
      for (int c = 0; c < 2; ++c) {
        int linear = c * 256 + tid;
        int r = linear >> 2, seg = linear & 3;
        gld_lds16(&A[(size_t)(m0 + r) * K + kc + kk * 32 + seg * 8],
                  &As[kk * 4096 + (size_t)(c * 256 + wave * 64) * 8]);
        gld_lds16(&Bt[(size_t)(n0 + r) * K + kc + kk * 32 + seg * 8],
                  &Bs[kk * 4096 + (size_t)(c * 256 + wave * 64) * 8]);
      }
    }
    __syncthreads();
#pragma unroll
    for (int kk = 0; kk < 2; ++kk) {
      bf16x8 af[4], bfr[4];
#pragma unroll
      for (int mi = 0; mi < 4; ++mi)
        af[mi] = *(const bf16x8*)&As[kk * 4096 + (wrow + mi * 16 + l15) * 32 + quad * 8];
#pragma unroll
      for (int ni = 0; ni < 4; ++ni)
        bfr[ni] = *(const bf16x8*)&Bs[kk * 4096 + (wcol + ni * 16 + l15) * 32 + quad * 8];
#pragma unroll
      for (int mi = 0; mi < 4; ++mi)
#pragma unroll
        for (int ni = 0; ni < 4; ++ni)
          acc[mi][ni] = __builtin_amdgcn_mfma_f32_16x16x32_bf16(af[mi], bfr[ni], acc[mi][ni], 0, 0, 0);
    }
    __syncthreads();
  }
#pragma unroll
  for (int mi = 0; mi < 4; ++mi) {
#pragma unroll
    for (int ni = 0; ni < 4; ++ni) {
#pragma unroll
      for (int r = 0; r < 4; ++r) {
        int m = m0 + wrow + mi * 16 + quad * 4 + r;
        int n = n0 + wcol + ni * 16 + l15;
        C[(size_t)m * N + n] = (OutT)acc[mi][ni][r];
      }
    }
  }
}

// ------------------------------------------------- RoPE on q,k + head-major relayout
// qkv rows (bf16): [q 2048 | k 512 | v 512]. qr: [B][H][T][DH], kr: [B][HKV][T][DH].
// Q is pre-scaled by log2(e)/sqrt(64) so flash's softmax is bare exp2(q.k).
__global__ __launch_bounds__(256) void rope_qk(const bf16_t* __restrict__ qkv,
                                               bf16_t* __restrict__ qr,
                                               bf16_t* __restrict__ kr) {
  int t = blockIdx.x, b = blockIdx.y;
  int tid = threadIdx.x;
  const bf16_t* row = qkv + (size_t)(b * T_ + t) * 3072;
  const float LN1E4_over32 = 9.210340371976184f / 32.0f;
  const float QSC = 1.44269504088896f * 0.125f;  // log2(e)/sqrt(64)
  for (int i = tid; i < 1024 + 256; i += 256) {
    bool isq = i < 1024;
    int ii = isq ? i : i - 1024;
    int hh = ii >> 5, j = ii & 31;
    int base = isq ? 0 : 2048;
    float inv = __expf(-(float)j * LN1E4_over32);
    float fr = (float)t * inv;
    float sn, cs;
    sincosf(fr, &sn, &cs);
    float x1 = (float)row[base + hh * 64 + j];
    float x2 = (float)row[base + hh * 64 + j + 32];
    float o1 = x1 * cs - x2 * sn;
    float o2 = x2 * cs + x1 * sn;
    if (isq) {
      size_t o = ((size_t)(b * H_ + hh) * T_ + t) * DH_;
      qr[o + j] = (bf16_t)(o1 * QSC);
      qr[o + j + 32] = (bf16_t)(o2 * QSC);
    } else {
      size_t o = ((size_t)(b * HKV_ + hh) * T_ + t) * DH_;
      kr[o + j] = (bf16_t)o1;
      kr[o + j + 32] = (bf16_t)o2;
    }
  }
}

// ----------------------------------------- V: transpose to [B][HKV][DH][T] (bf16)
// Columns (kv positions) within each 64-wide tile are stored PERMUTED by
// f(n) = 32*b5 + 16*b2 + 4*(b4b3) + (b1b0)  (n bits b5..b0), so that flash's
// PV A-fragment (P values) is lane-local after the swapped QK^T:
//   lane(l15,quad) holds P[q=l15][kv=16mt+4quad+r]; PV k-slot (k0,quad,j) reads
//   stored col n=32k0+8quad+j which now contains true kv 32k0+16(j>>2)+4quad+(j&3)
//   = the held element (mt=2k0+(j>>2), r=j&3). No cross-lane / LDS P traffic.
__global__ __launch_bounds__(256) void transpose_v(const bf16_t* __restrict__ qkv,
                                                   bf16_t* __restrict__ vtr) {
  __shared__ __align__(16) bf16_t tile[64][72];
  int t0 = blockIdx.x * 64;
  int hk = blockIdx.y;
  int b = blockIdx.z;
  int tid = threadIdx.x;
  for (int i = tid; i < 512; i += 256) {
    int r = i >> 3, s = i & 7;
    *(bf16x8*)&tile[r][s * 8] =
        *(const bf16x8*)&qkv[(size_t)(b * T_ + t0 + r) * 3072 + 2560 + hk * 64 + s * 8];
  }
  __syncthreads();
  for (int i = tid; i < 4096; i += 256) {
    int dd = i >> 6, tt = i & 63;
    int src = (tt & 32) | ((tt & 4) << 2) | ((tt & 24) >> 1) | (tt & 3);
    vtr[((size_t)(b * HKV_ + hk) * DH_ + dd) * T_ + t0 + tt] = tile[src][dd];
  }
}

// ---------------------------------------------------------------- flash attention v7
// grid (8 pairs, H, B), 256 threads (4 waves). Block handles a 128-row Q-tile
// pair (qtA=i, qtB=15-i) -> constant work (nkvA+nkvB = 34 kv tiles of 64).
// Wave owns q rows [w*32, w*32+32) of BOTH halves as two 16-row fragments.
// Per kv tile: 8 K-frag + 8 V-frag ds_read_b128 feed up to 16 QK + 16 PV MFMAs
// (2 rg x 2 halves) -- 2.6x less LDS-read traffic per CU than v6.
// KV tiles double-buffered: ONE barrier per tile. Safety: a wave depositing
// tile kv passed barrier(kv-1), which guarantees all waves finished
// compute(kv-2) -- the last readers of buf[kv&1].
__global__ __launch_bounds__(256) void flash_attn(const bf16_t* __restrict__ qr,
                                                  const bf16_t* __restrict__ kr,
                                                  const bf16_t* __restrict__ vtr,
                                                  bf16_t* __restrict__ ctxb) {
  __shared__ __align__(16) bf16_t Ks[2][64 * 72];
  __shared__ __align__(16) bf16_t Vt[2][64 * 72];
  int tid = threadIdx.x;
  int lane = tid & 63;
  int wave = tid >> 6;
  int l15 = lane & 15, quad = lane >> 4;
  int pair = blockIdx.x, h = blockIdx.y, b = blockIdx.z;
  int qtA = pair, qtB = 15 - pair;  // 128-row Q tiles; qtA < qtB always
  int nkvA = 2 * qtA + 2, nkvB = 2 * qtB + 2;
  int kvh = h >> 2;

  const bf16_t* qbase = qr + (size_t)(b * H_ + h) * T_ * DH_;
  const bf16_t* kbase = kr + (size_t)(b * HKV_ + kvh) * T_ * DH_;
  const bf16_t* vbase = vtr + (size_t)(b * HKV_ + kvh) * DH_ * T_;

  int rowA = qtA * 128 + wave * 32;  // wave's first q row, half A
  int rowB = qtB * 128 + wave * 32;

  // Q fragments (B-operand layout: lane l15 = qrow-in-frag, k = quad*8+j)
  bf16x8 qA[2][2], qB[2][2];
#pragma unroll
  for (int rg = 0; rg < 2; ++rg)
#pragma unroll
    for (int k0 = 0; k0 < 2; ++k0) {
      qA[rg][k0] = *(const bf16x8*)&qbase[(size_t)(rowA + rg * 16 + l15) * 64 + k0 * 32 + quad * 8];
      qB[rg][k0] = *(const bf16x8*)&qbase[(size_t)(rowB + rg * 16 + l15) * 64 + k0 * 32 + quad * 8];
    }

  f32x4 oA[2][4] = {}, oB[2][4] = {};
  float lA0 = 0.f, lA1 = 0.f, lB0 = 0.f, lB1 = 0.f;

  bf16x8 kreg[2], vreg[2];
  auto load_kv = [&](int kv) {
#pragma unroll
    for (int c = 0; c < 2; ++c) {
      int idx = c * 256 + tid;
      int r = idx >> 3, sg = idx & 7;
      kreg[c] = *(const bf16x8*)&kbase[(size_t)kv * 4096 + r * 64 + sg * 8];
      vreg[c] = *(const bf16x8*)&vbase[(size_t)r * T_ + kv * 64 + sg * 8];
    }
  };
  load_kv(0);

  for (int kv = 0; kv < nkvB; ++kv) {
    bf16_t* ks = Ks[kv & 1];
    bf16_t* vt = Vt[kv & 1];
    // deposit prefetched K/V tile into this iteration's buffer
#pragma unroll
    for (int c = 0; c < 2; ++c) {
      int idx = c * 256 + tid;
      int r = idx >> 3, sg = idx & 7;
      *(bf16x8*)&ks[r * 72 + sg * 8] = kreg[c];
      *(bf16x8*)&vt[r * 72 + sg * 8] = vreg[c];
    }
    __syncthreads();
    if (kv + 1 < nkvB) load_kv(kv + 1);

    bool actA = kv < nkvA;

    // ---- QK^T: shared K fragments feed both halves & both row-groups
    f32x4 sA[2][4] = {}, sB[2][4] = {};
#pragma unroll
    for (int mt = 0; mt < 4; ++mt) {
      bf16x8 ak0 = *(const bf16x8*)&ks[(mt * 16 + l15) * 72 + quad * 8];
      bf16x8 ak1 = *(const bf16x8*)&ks[(mt * 16 + l15) * 72 + 32 + quad * 8];
#pragma unroll
      for (int rg = 0; rg < 2; ++rg) {
        sB[rg][mt] = __builtin_amdgcn_mfma_f32_16x16x32_bf16(ak0, qB[rg][0], sB[rg][mt], 0, 0, 0);
        sB[rg][mt] = __builtin_amdgcn_mfma_f32_16x16x32_bf16(ak1, qB[rg][1], sB[rg][mt], 0, 0, 0);
      }
      if (actA) {
#pragma unroll
        for (int rg = 0; rg < 2; ++rg) {
          sA[rg][mt] = __builtin_amdgcn_mfma_f32_16x16x32_bf16(ak0, qA[rg][0], sA[rg][mt], 0, 0, 0);
          sA[rg][mt] = __builtin_amdgcn_mfma_f32_16x16x32_bf16(ak1, qA[rg][1], sA[rg][mt], 0, 0, 0);
        }
      }
    }

    // ---- causal mask (only the two diagonal tiles per half)
    int ct = kv * 64;
    if (kv >= 2 * qtB) {
#pragma unroll
      for (int rg = 0; rg < 2; ++rg)
#pragma unroll
        for (int mt = 0; mt < 4; ++mt)
#pragma unroll
          for (int r = 0; r < 4; ++r)
            if (ct + mt * 16 + quad * 4 + r > rowB + rg * 16 + l15) sB[rg][mt][r] = -1e30f;
    }
    if (actA && kv >= 2 * qtA) {
#pragma unroll
      for (int rg = 0; rg < 2; ++rg)
#pragma unroll
        for (int mt = 0; mt < 4; ++mt)
#pragma unroll
          for (int r = 0; r < 4; ++r)
            if (ct + mt * 16 + quad * 4 + r > rowA + rg * 16 + l15) sA[rg][mt][r] = -1e30f;
    }

    // ---- exp2 + in-register pack (V column permutation makes pa lane-local)
    bf16x8 paA[2][2], paB[2][2];
#pragma unroll
    for (int rg = 0; rg < 2; ++rg)
#pragma unroll
      for (int k0 = 0; k0 < 2; ++k0)
#pragma unroll
        for (int hh = 0; hh < 2; ++hh)
#pragma unroll
          for (int r = 0; r < 4; ++r) {
            float p = fast_exp2(sB[rg][2 * k0 + hh][r]);
            if (rg == 0) lB0 += p; else lB1 += p;
            paB[rg][k0][hh * 4 + r] = (bf16_t)p;
          }
    if (actA) {
#pragma unroll
      for (int rg = 0; rg < 2; ++rg)
#pragma unroll
        for (int k0 = 0; k0 < 2; ++k0)
#pragma unroll
          for (int hh = 0; hh < 2; ++hh)
#pragma unroll
            for (int r = 0; r < 4; ++r) {
              float p = fast_exp2(sA[rg][2 * k0 + hh][r]);
              if (rg == 0) lA0 += p; else lA1 += p;
              paA[rg][k0][hh * 4 + r] = (bf16_t)p;
            }
    }

    // ---- PV: shared V fragments feed both halves & both row-groups
#pragma unroll
    for (int k0 = 0; k0 < 2; ++k0) {
#pragma unroll
      for (int dn = 0; dn < 4; ++dn) {
        bf16x8 bv = *(const bf16x8*)&vt[(dn * 16 + l15) * 72 + k0 * 32 + quad * 8];
#pragma unroll
        for (int rg = 0; rg < 2; ++rg)
          oB[rg][dn] = __builtin_amdgcn_mfma_f32_16x16x32_bf16(paB[rg][k0], bv, oB[rg][dn], 0, 0, 0);
        if (actA) {
#pragma unroll
          for (int rg = 0; rg < 2; ++rg)
            oA[rg][dn] = __builtin_amdgcn_mfma_f32_16x16x32_bf16(paA[rg][k0], bv, oA[rg][dn], 0, 0, 0);
        }
      }
    }
  }

  // epilogue: reduce l across quads, normalize, write ctxb [B][T][H*DH]
  lA0 += __shfl_xor(lA0, 16, 64); lA0 += __shfl_xor(lA0, 32, 64);
  lA1 += __shfl_xor(lA1, 16, 64); lA1 += __shfl_xor(lA1, 32, 64);
  lB0 += __shfl_xor(lB0, 16, 64); lB0 += __shfl_xor(lB0, 32, 64);
  lB1 += __shfl_xor(lB1, 16, 64); lB1 += __shfl_xor(lB1, 32, 64);
  float iA0 = 1.0f / lA0, iA1 = 1.0f / lA1, iB0 = 1.0f / lB0, iB1 = 1.0f / lB1;
#pragma unroll
  for (int r = 0; r < 4; ++r) {
    float vA0 = __shfl(iA0, quad * 4 + r, 64);
    float vA1 = __shfl(iA1, quad * 4 + r, 64);
    float vB0 = __shfl(iB0, quad * 4 + r, 64);
    float vB1 = __shfl(iB1, quad * 4 + r, 64);
    int tA0 = rowA + quad * 4 + r;
    int tA1 = rowA + 16 + quad * 4 + r;
    int tB0 = rowB + quad * 4 + r;
    int tB1 = rowB + 16 + quad * 4 + r;
#pragma unroll
    for (int dn = 0; dn < 4; ++dn) {
      ctxb[(size_t)(b * T_ + tA0) * D_ + h * 64 + dn * 16 + l15] = (bf16_t)(oA[0][dn][r] * vA0);
      ctxb[(size_t)(b * T_ + tA1) * D_ + h * 64 + dn * 16 + l15] = (bf16_t)(oA[1][dn][r] * vA1);
      ctxb[(size_t)(b * T_ + tB0) * D_ + h * 64 + dn * 16 + l15] = (bf16_t)(oB[0][dn][r] * vB0);
      ctxb[(size_t)(b * T_ + tB1) * D_ + h * 64 + dn * 16 + l15] = (bf16_t)(oB[1][dn][r] * vB1);
    }
  }
}

// ---------------------------------------------------------------------- launcher
extern "C" void kernel_launch(void* const* d_in, const int* in_sizes, int n_in,
                              void* d_out, int out_size, void* d_ws, size_t ws_size,
                              hipStream_t stream) {
  const float* x = (const float*)d_in[0];
  const float* Wq = (const float*)d_in[1];
  const float* Wk = (const float*)d_in[2];
  const float* Wv = (const float*)d_in[3];
  const float* Wo = (const float*)d_in[4];
  float* out = (float*)d_out;

  char* ws = (char*)d_ws;
  size_t off = 0;
  bf16_t* xb = (bf16_t*)(ws + off); off += (size_t)B_ * T_ * D_ * 2;
  bf16_t* wqkvb = (bf16_t*)(ws + off); off += (size_t)3072 * 2048 * 2;
  bf16_t* wob = (bf16_t*)(ws + off); off += (size_t)2048 * 2048 * 2;
  bf16_t* qkv = (bf16_t*)(ws + off); off += (size_t)4096 * 3072 * 2;
  bf16_t* qr = (bf16_t*)(ws + off); off += (size_t)B_ * H_ * T_ * DH_ * 2;
  bf16_t* kr = (bf16_t*)(ws + off); off += (size_t)B_ * HKV_ * T_ * DH_ * 2;
  bf16_t* vtr = (bf16_t*)(ws + off); off += (size_t)B_ * HKV_ * T_ * DH_ * 2;
  bf16_t* ctxb = (bf16_t*)(ws + off); off += (size_t)B_ * T_ * D_ * 2;

  int nx = B_ * T_ * D_;
  cast_f32_bf16<<<nx / 8 / 256, 256, 0, stream>>>(x, xb, nx);
  transpose_wqkv<<<dim3(3072 / 64, 2048 / 64), 256, 0, stream>>>(Wq, Wk, Wv, wqkvb);
  transpose_w<<<dim3(2048 / 64, 2048 / 64), 256, 0, stream>>>(Wo, wob, 2048, 2048);

  gemm_bt<bf16_t><<<dim3(3072 / 128, 4096 / 128), 256, 0, stream>>>(xb, wqkvb, qkv, 4096, 3072, 2048);

  rope_qk<<<dim3(T_, B_), 256, 0, stream>>>(qkv, qr, kr);
  transpose_v<<<dim3(T_ / 64, HKV_, B_), 256, 0, stream>>>(qkv, vtr);

  flash_attn<<<dim3(8, H_, B_), 256, 0, stream>>>(qr, kr, vtr, ctxb);

  gemm_bt<float><<<dim3(2048 / 128, 4096 / 128), 256, 0, stream>>>(ctxb, wob, out, 4096, 2048, 2048);
}